// Round 1
// baseline (295.249 us; speedup 1.0000x reference)
//
#include <hip/hip_runtime.h>
#include <math.h>

#define B5 5
#define DX 4096
#define DT 4096
#define DR 4097   // T + D

// ---------------- workspace layout (floats) ----------------
enum {
  WS_H1   = 0,                    // 5*4096 accum (zeroed)
  WS_QXI  = WS_H1  + 20480,
  WS_LQC  = WS_QXI + 20480,
  WS_ZM   = WS_LQC + 20480,
  WS_ZC   = WS_ZM  + 20480,
  WS_H23  = WS_ZC  + 20480,
  WS_RM   = WS_H23 + 20480,       // 5*4097
  WS_RC   = WS_RM  + 20485,
  WS_H3   = WS_RC  + 20485,
  WS_XM   = WS_H3  + 20480,
  WS_XC   = WS_XM  + 20480,
  WS_KLD1 = WS_XC  + 20480,
  WS_KLD2,
  WS_NLL,
  WS_ACCUM_END,
  // not zeroed (always written before read each call):
  WS_XIV   = WS_ACCUM_END,        // xi 20480
  WS_QXI_F = WS_XIV   + 20480,
  WS_LQC_F = WS_QXI_F + 20480,
  WS_Z     = WS_LQC_F + 20480,
  WS_KSS   = WS_Z + 20480,        // 25
  WS_KXS   = WS_KSS + 25,         // 25
  WS_F     = WS_KXS + 25,         // 5
  WS_QFM   = WS_F + 5,            // 5
  WS_QFC   = WS_QFM + 5,          // 5
  WS_END
};

#define GROWS  64
#define GBLOCK 256

// ---------------- GEMM: Y[5,dout] (+)= prolog(X)[5,din] @ W ----------------
// PROLOG: 0 raw, 1 relu(X+bias[aux1]), 2 relu(f[b]*W2[aux1]+b2[aux2]), 3 concat(x[X], z[aux1])
template<int PROLOG, int DUAL, int ALIGNED>
__global__ __launch_bounds__(GBLOCK) void gemm5(
    const float* __restrict__ X,    const float* __restrict__ aux1,
    const float* __restrict__ aux2, const float* __restrict__ fvec,
    const float* __restrict__ Wa,   const float* __restrict__ Wb,
    float* __restrict__ Ya,         float* __restrict__ Yb,
    int din, int dout)
{
  __shared__ float sx[B5][GROWS];
  const int tid = threadIdx.x;
  const long i0 = (long)blockIdx.y * GROWS;

  for (int t = tid; t < B5 * GROWS; t += GBLOCK) {
    int b  = t / GROWS;
    int il = t % GROWS;
    int i  = (int)i0 + il;
    float v;
    if (PROLOG == 0)      v = X[b * din + i];
    else if (PROLOG == 1) v = fmaxf(X[b * din + i] + aux1[i], 0.f);
    else if (PROLOG == 2) v = fmaxf(fvec[b] * aux1[i] + aux2[i], 0.f);
    else                  v = (i < DX) ? X[b * DX + i] : aux1[b * DX + (i - DX)];
    sx[b][il] = v;
  }
  __syncthreads();

  long o0 = ((long)blockIdx.x * GBLOCK + tid) * 2;
  if (o0 >= dout) return;
  const bool has2 = (o0 + 1 < dout);

  float accA[B5][2] = {};
  float accB[B5][2] = {};

  const float* wa = Wa + i0 * dout + o0;
  const float* wb = DUAL ? (Wb + i0 * dout + o0) : nullptr;

  #pragma unroll 4
  for (int il = 0; il < GROWS; ++il) {
    float w0a, w1a, w0b = 0.f, w1b = 0.f;
    if (ALIGNED) {
      float2 ta = *(const float2*)wa; w0a = ta.x; w1a = ta.y;
      if (DUAL) { float2 tb = *(const float2*)wb; w0b = tb.x; w1b = tb.y; }
    } else {
      w0a = wa[0]; w1a = has2 ? wa[1] : 0.f;
      if (DUAL) { w0b = wb[0]; w1b = has2 ? wb[1] : 0.f; }
    }
    #pragma unroll
    for (int b = 0; b < B5; ++b) {
      float xv = sx[b][il];
      accA[b][0] += xv * w0a; accA[b][1] += xv * w1a;
      if (DUAL) { accB[b][0] += xv * w0b; accB[b][1] += xv * w1b; }
    }
    wa += dout; if (DUAL) wb += dout;
  }

  #pragma unroll
  for (int b = 0; b < B5; ++b) {
    atomicAdd(&Ya[(long)b * dout + o0], accA[b][0]);
    if (has2) atomicAdd(&Ya[(long)b * dout + o0 + 1], accA[b][1]);
    if (DUAL) {
      atomicAdd(&Yb[(long)b * dout + o0], accB[b][0]);
      if (has2) atomicAdd(&Yb[(long)b * dout + o0 + 1], accB[b][1]);
    }
  }
}

// ---------------- helpers ----------------
__device__ inline float wave_sum(float v) {
  #pragma unroll
  for (int o = 32; o > 0; o >>= 1) v += __shfl_down(v, o, 64);
  return v;
}

// ---------------- xi = exp(0.5*lqc)*eps + qxi_mean ----------------
__global__ void k_xi(const float* __restrict__ qraw, const float* __restrict__ lraw,
                     const float* __restrict__ b11,  const float* __restrict__ b12,
                     const float* __restrict__ eps_xi,
                     float* __restrict__ qf, float* __restrict__ lf, float* __restrict__ xiv)
{
  int idx = blockIdx.x * 256 + threadIdx.x;
  if (idx >= B5 * DT) return;
  int col = idx & (DT - 1);
  float qm = qraw[idx] + b11[col];
  float lq = lraw[idx] + b12[col];
  qf[idx] = qm; lf[idx] = lq;
  xiv[idx] = expf(0.5f * lq) * eps_xi[idx] + qm;
}

// ---------------- ARD kernel entries: 50 blocks ----------------
__global__ __launch_bounds__(256) void k_ard(
    const float* __restrict__ s, const float* __restrict__ xiv,
    const float* __restrict__ w, const float* __restrict__ sigma,
    float* __restrict__ Kss, float* __restrict__ Kxs)
{
  int bid = blockIdx.x;
  int i, j;
  const float* a;
  if (bid < 25) { i = bid / 5; j = bid % 5; a = s + i * DT; }
  else          { int k = bid - 25; i = k / 5; j = k % 5; a = xiv + i * DT; }
  const float* bb = s + j * DT;

  float sum = 0.f;
  for (int t = threadIdx.x; t < DT; t += 256) {
    float d = a[t] - bb[t];
    sum += w[t] * d * d;
  }
  sum = wave_sum(sum);
  __shared__ float red[4];
  int lane = threadIdx.x & 63, wv = threadIdx.x >> 6;
  if (lane == 0) red[wv] = sum;
  __syncthreads();
  if (threadIdx.x == 0) {
    float tot = red[0] + red[1] + red[2] + red[3];
    float sg = sigma[0];
    float K = sg * sg * expf(-0.5f * tot);
    if (bid < 25) Kss[i * 5 + j] = K; else Kxs[i * 5 + j] = K;
  }
}

// ---------------- GP solve: 5x5 inverse + f ----------------
__global__ void k_gp(const float* __restrict__ Kss, const float* __restrict__ Kxs,
                     const float* __restrict__ t_in, const float* __restrict__ eps_f,
                     const float* __restrict__ sigma,
                     float* __restrict__ fv, float* __restrict__ qfm, float* __restrict__ qfc)
{
  if (threadIdx.x != 0) return;
  double M[5][5], Inv[5][5];
  for (int i = 0; i < 5; ++i)
    for (int j = 0; j < 5; ++j) { M[i][j] = Kss[i * 5 + j]; Inv[i][j] = (i == j) ? 1.0 : 0.0; }
  // Gauss-Jordan with partial pivoting
  for (int c = 0; c < 5; ++c) {
    int p = c; double best = fabs(M[c][c]);
    for (int r = c + 1; r < 5; ++r) if (fabs(M[r][c]) > best) { best = fabs(M[r][c]); p = r; }
    if (p != c)
      for (int k = 0; k < 5; ++k) {
        double tm = M[c][k]; M[c][k] = M[p][k]; M[p][k] = tm;
        tm = Inv[c][k]; Inv[c][k] = Inv[p][k]; Inv[p][k] = tm;
      }
    double pivinv = 1.0 / M[c][c];
    for (int k = 0; k < 5; ++k) { M[c][k] *= pivinv; Inv[c][k] *= pivinv; }
    for (int r = 0; r < 5; ++r) if (r != c) {
      double m = M[r][c];
      for (int k = 0; k < 5; ++k) { M[r][k] -= m * M[c][k]; Inv[r][k] -= m * Inv[c][k]; }
    }
  }
  double kk[5][5];
  for (int i = 0; i < 5; ++i)
    for (int j = 0; j < 5; ++j) {
      double sum = 0.0;
      for (int k = 0; k < 5; ++k) sum += (double)Kxs[i * 5 + k] * Inv[k][j];
      kk[i][j] = sum;
    }
  double sg = sigma[0], s2 = sg * sg;
  for (int i = 0; i < 5; ++i) {
    double qm = 0.0, qc = s2;
    for (int j = 0; j < 5; ++j) { qm += kk[i][j] * (double)t_in[j]; qc -= kk[i][j] * (double)Kxs[i * 5 + j]; }
    if (qc < 1e-12) qc = 1e-12;
    qfm[i] = (float)qm;
    qfc[i] = (float)qc;
    fv[i]  = sqrtf((float)qc) * eps_f[i] + (float)qm;
  }
}

// ---------------- z stage + kld1 partial ----------------
__global__ void k_z(const float* __restrict__ zmraw, const float* __restrict__ zcraw,
                    const float* __restrict__ b21,   const float* __restrict__ b22,
                    const float* __restrict__ eps_z,
                    float* __restrict__ out_zm, float* __restrict__ out_zc,
                    float* __restrict__ zv, float* __restrict__ kld1sum)
{
  int idx = blockIdx.x * 256 + threadIdx.x;
  float term = 0.f;
  if (idx < B5 * DT) {
    int col = idx & (DT - 1);
    float zm = zmraw[idx] + b21[col];
    float zc = zcraw[idx] + b22[col];
    out_zm[idx] = zm; out_zc[idx] = zc;
    zv[idx] = expf(0.5f * zc) * eps_z[idx] + zm;
    term = -zc - 1.f + expf(zc) + zm * zm;
  }
  term = wave_sum(term);
  if ((threadIdx.x & 63) == 0) atomicAdd(kld1sum, term);
}

// ---------------- r stage + kld2 partial ----------------
__global__ void k_r(const float* __restrict__ rmraw, const float* __restrict__ rcraw,
                    const float* __restrict__ b24,   const float* __restrict__ b25,
                    const float* __restrict__ qxi,   const float* __restrict__ lqc,
                    const float* __restrict__ qfm,   const float* __restrict__ qfc,
                    float* __restrict__ kld2sum)
{
  int idx = blockIdx.x * 256 + threadIdx.x;
  float term = 0.f;
  if (idx < B5 * DR) {
    int b = idx / DR, col = idx % DR;
    float rm = rmraw[idx] + b24[col];
    float rc = rcraw[idx] + b25[col];
    float qm, qc;
    if (col < DT) { qm = qxi[b * DT + col]; qc = lqc[b * DT + col]; }
    else          { qm = qfm[b];            qc = logf(qfc[b]); }
    float d = qm - rm;
    term = rc - qc - 1.f + expf(qc - rc) + d * d * expf(-rc);
  }
  term = wave_sum(term);
  if ((threadIdx.x & 63) == 0) atomicAdd(kld2sum, term);
}

// ---------------- x stage + nll partial ----------------
__global__ void k_x(const float* __restrict__ xmraw, const float* __restrict__ xcraw,
                    const float* __restrict__ b31,   const float* __restrict__ b32,
                    const float* __restrict__ x,
                    float* __restrict__ out_xm, float* __restrict__ out_xc,
                    float* __restrict__ nllsum)
{
  int idx = blockIdx.x * 256 + threadIdx.x;
  float term = 0.f;
  if (idx < B5 * DX) {
    int col = idx & (DX - 1);
    float xm = xmraw[idx] + b31[col];
    float xc = xcraw[idx] + b32[col];
    out_xm[idx] = xm; out_xc[idx] = xc;
    float d = x[idx] - xm;
    term = 1.14472988584940017f + xc + expf(-xc) * d * d;  // ln(pi) + ...
  }
  term = wave_sum(term);
  if ((threadIdx.x & 63) == 0) atomicAdd(nllsum, term);
}

// ---------------- finalize scalars ----------------
__global__ void k_fin(const float* __restrict__ sums, float* __restrict__ out)
{
  if (threadIdx.x == 0) {
    out[0] = 0.5f * (sums[0] + sums[1]) / (float)B5;
    out[1] = 0.5f * sums[2] / (float)B5;
  }
}

// ---------------- launch ----------------
extern "C" void kernel_launch(void* const* d_in, const int* in_sizes, int n_in,
                              void* d_out, int out_size, void* d_ws, size_t ws_size,
                              hipStream_t stream)
{
  const float* x      = (const float*)d_in[0];
  const float* eps_xi = (const float*)d_in[1];
  const float* eps_f  = (const float*)d_in[2];
  const float* eps_z  = (const float*)d_in[3];
  const float* W1  = (const float*)d_in[4];  const float* b1  = (const float*)d_in[5];
  const float* W11 = (const float*)d_in[6];  const float* b11 = (const float*)d_in[7];
  const float* W12 = (const float*)d_in[8];  const float* b12 = (const float*)d_in[9];
  const float* W2  = (const float*)d_in[10]; const float* b2  = (const float*)d_in[11];
  const float* W21 = (const float*)d_in[12]; const float* b21 = (const float*)d_in[13];
  const float* W22 = (const float*)d_in[14]; const float* b22 = (const float*)d_in[15];
  const float* W23 = (const float*)d_in[16]; const float* b23 = (const float*)d_in[17];
  const float* W24 = (const float*)d_in[18]; const float* b24 = (const float*)d_in[19];
  const float* W25 = (const float*)d_in[20]; const float* b25 = (const float*)d_in[21];
  const float* W3  = (const float*)d_in[22]; const float* b3  = (const float*)d_in[23];
  const float* W31 = (const float*)d_in[24]; const float* b31 = (const float*)d_in[25];
  const float* W32 = (const float*)d_in[26]; const float* b32 = (const float*)d_in[27];
  const float* s     = (const float*)d_in[28];
  const float* t     = (const float*)d_in[29];
  const float* sigma = (const float*)d_in[30];
  const float* w     = (const float*)d_in[31];

  float* ws  = (float*)d_ws;
  float* out = (float*)d_out;

  // zero split-K accumulators + loss scalars (every call: deterministic)
  hipMemsetAsync(ws, 0, (size_t)WS_ACCUM_END * sizeof(float), stream);

  dim3 blk(256);

  // h1_raw = x @ W1
  gemm5<0,0,1><<<dim3(8,64), blk, 0, stream>>>(x, nullptr, nullptr, nullptr,
      W1, nullptr, ws + WS_H1, nullptr, 4096, 4096);
  // [qxi_raw, lqc_raw] = relu(h1_raw + b1) @ [W11, W12]
  gemm5<1,1,1><<<dim3(8,64), blk, 0, stream>>>(ws + WS_H1, b1, nullptr, nullptr,
      W11, W12, ws + WS_QXI, ws + WS_LQC, 4096, 4096);
  // xi (+finalized qxi_mean / log_qxi_cov)
  k_xi<<<80, blk, 0, stream>>>(ws + WS_QXI, ws + WS_LQC, b11, b12, eps_xi,
      ws + WS_QXI_F, ws + WS_LQC_F, ws + WS_XIV);
  // ARD entries K_ss (25) + K_xs (25)
  k_ard<<<50, blk, 0, stream>>>(s, ws + WS_XIV, w, sigma, ws + WS_KSS, ws + WS_KXS);
  // GP solve: inverse, qf_mean, qf_cov, f
  k_gp<<<1, 64, 0, stream>>>(ws + WS_KSS, ws + WS_KXS, t, eps_f, sigma,
      ws + WS_F, ws + WS_QFM, ws + WS_QFC);
  // [zm_raw, zc_raw] = h2 @ [W21, W22], h2 = relu(f*W2+b2) computed in prolog
  gemm5<2,1,1><<<dim3(8,64), blk, 0, stream>>>(nullptr, W2, b2, ws + WS_F,
      W21, W22, ws + WS_ZM, ws + WS_ZC, 4096, 4096);
  // z outputs + z sample + kld1
  k_z<<<80, blk, 0, stream>>>(ws + WS_ZM, ws + WS_ZC, b21, b22, eps_z,
      out + 2, out + 2 + 20480, ws + WS_Z, ws + WS_KLD1);
  // h23_raw = concat(x, z) @ W23
  gemm5<3,0,1><<<dim3(8,128), blk, 0, stream>>>(x, ws + WS_Z, nullptr, nullptr,
      W23, nullptr, ws + WS_H23, nullptr, 8192, 4096);
  // [rm_raw, rc_raw] = relu(h23_raw + b23) @ [W24, W25]  (dout = 4097, unaligned)
  gemm5<1,1,0><<<dim3(9,64), blk, 0, stream>>>(ws + WS_H23, b23, nullptr, nullptr,
      W24, W25, ws + WS_RM, ws + WS_RC, 4096, 4097);
  // kld2
  k_r<<<81, blk, 0, stream>>>(ws + WS_RM, ws + WS_RC, b24, b25,
      ws + WS_QXI_F, ws + WS_LQC_F, ws + WS_QFM, ws + WS_QFC, ws + WS_KLD2);
  // h3_raw = z @ W3
  gemm5<0,0,1><<<dim3(8,64), blk, 0, stream>>>(ws + WS_Z, nullptr, nullptr, nullptr,
      W3, nullptr, ws + WS_H3, nullptr, 4096, 4096);
  // [xm_raw, xc_raw] = relu(h3_raw + b3) @ [W31, W32]
  gemm5<1,1,1><<<dim3(8,64), blk, 0, stream>>>(ws + WS_H3, b3, nullptr, nullptr,
      W31, W32, ws + WS_XM, ws + WS_XC, 4096, 4096);
  // x outputs + nll
  k_x<<<80, blk, 0, stream>>>(ws + WS_XM, ws + WS_XC, b31, b32, x,
      out + 2 + 40960, out + 2 + 61440, ws + WS_NLL);
  // scalars
  k_fin<<<1, 64, 0, stream>>>(ws + WS_KLD1, out);
}